// Round 1
// baseline (33.995 us; speedup 1.0000x reference)
//
#include <hip/hip_runtime.h>
#include <math.h>

// Poisson MC estimator: v_hat (B,) and gradv_hat (B,3) from pairwise
// regularized Green's function over M landmarks.
//
// Layout decisions:
//  - block = 512 threads = 8 waves; wave w handles landmark slice
//    [w*256, (w+1)*256); each lane owns TWO queries (lane, lane+64) so the
//    broadcast LDS read per landmark is amortized over 2 queries' VALU work.
//  - Landmarks staged once in LDS as float4(-2y0,-2y1,-2y2,||y||^2) + g.
//    All 64 lanes of a wave read the same address -> broadcast, no conflicts.
//  - Per-(wave,query) partials reduced through LDS; each output element is
//    written exactly once -> deterministic, no atomics, no workspace.

#define EPS2      1e-4f                    // cfg.eps^2
#define INV_4PI   0.07957747154594767f

constexpr int M_LAND = 2048;
constexpr int NW     = 8;                  // waves (slices) per block
constexpr int SLICE  = M_LAND / NW;        // 256 landmarks per wave
constexpr int QPB    = 128;                // queries per block (64 lanes x 2)

__global__ __launch_bounds__(512, 2)
void poisson_mc_kernel(const float* __restrict__ xq,
                       const float* __restrict__ xl,
                       const float* __restrict__ gl,
                       float* __restrict__ out,
                       int B)
{
    __shared__ float4 pack[M_LAND];        // 32 KB: (-2y0,-2y1,-2y2,||y||^2)
    __shared__ float  gsh[M_LAND];         //  8 KB
    __shared__ float  part[NW][QPB][5];    // 20 KB: av, ac, ax, ay, az

    const int tid = threadIdx.x;

    // ---- stage landmarks (one-time, 4 per thread) ----
    for (int j = tid; j < M_LAND; j += 512) {
        float l0 = xl[3*j + 0];
        float l1 = xl[3*j + 1];
        float l2 = xl[3*j + 2];
        float n2 = l0*l0 + l1*l1 + l2*l2;
        pack[j] = make_float4(-2.0f*l0, -2.0f*l1, -2.0f*l2, n2);
        gsh[j]  = gl[j];
    }

    const int lane  = tid & 63;
    const int w     = tid >> 6;            // wave id = landmark slice id
    const int qbase = blockIdx.x * QPB;
    const int qa    = qbase + lane;        // query A
    const int qb    = qbase + 64 + lane;   // query B

    const float a0 = xq[3*qa+0], a1 = xq[3*qa+1], a2 = xq[3*qa+2];
    const float b0 = xq[3*qb+0], b1 = xq[3*qb+1], b2 = xq[3*qb+2];
    // fold eps^2 into the per-query constant:  t_raw = (q.q + eps2) + y.y - 2 q.y
    const float qea = a0*a0 + a1*a1 + a2*a2 + EPS2;
    const float qeb = b0*b0 + b1*b1 + b2*b2 + EPS2;

    __syncthreads();

    float av_a = 0.f, ac_a = 0.f, ax_a = 0.f, ay_a = 0.f, az_a = 0.f;
    float av_b = 0.f, ac_b = 0.f, ax_b = 0.f, ay_b = 0.f, az_b = 0.f;

    const int base = w * SLICE;
#pragma unroll 8
    for (int i = 0; i < SLICE; ++i) {
        const float4 p = pack[base + i];   // broadcast ds_read_b128
        const float  g = gsh[base + i];    // broadcast ds_read_b32

        // query A
        float ta = fmaf(p.x, a0, fmaf(p.y, a1, fmaf(p.z, a2, qea + p.w)));
        ta = fmaxf(ta, EPS2);              // == maximum(r2,0)+eps^2 exactly
        float sa  = __builtin_amdgcn_rsqf(ta);   // v_rsq_f32
        float s2a = sa * sa;
        float s3a = s2a * sa;
        float ca  = g * s3a;
        av_a = fmaf(g, sa, av_a);
        ac_a += ca;
        ax_a = fmaf(ca, p.x, ax_a);        // accumulates c * (-2 y0)
        ay_a = fmaf(ca, p.y, ay_a);
        az_a = fmaf(ca, p.z, az_a);

        // query B
        float tb = fmaf(p.x, b0, fmaf(p.y, b1, fmaf(p.z, b2, qeb + p.w)));
        tb = fmaxf(tb, EPS2);
        float sb  = __builtin_amdgcn_rsqf(tb);
        float s2b = sb * sb;
        float s3b = s2b * sb;
        float cb  = g * s3b;
        av_b = fmaf(g, sb, av_b);
        ac_b += cb;
        ax_b = fmaf(cb, p.x, ax_b);
        ay_b = fmaf(cb, p.y, ay_b);
        az_b = fmaf(cb, p.z, az_b);
    }

    // ---- write per-(wave, query) partials ----
    part[w][lane][0] = av_a;  part[w][lane][1] = ac_a;
    part[w][lane][2] = ax_a;  part[w][lane][3] = ay_a;  part[w][lane][4] = az_a;
    part[w][lane+64][0] = av_b;  part[w][lane+64][1] = ac_b;
    part[w][lane+64][2] = ax_b;  part[w][lane+64][3] = ay_b;  part[w][lane+64][4] = az_b;

    __syncthreads();

    // ---- reduce: 512 threads = 128 queries x 4 output components ----
    const int q   = tid >> 2;              // 0..127
    const int cmp = tid & 3;               // 0: v, 1..3: grad components
    const int qg  = qbase + q;

    if (cmp == 0) {
        float s = 0.f;
        #pragma unroll
        for (int ww = 0; ww < NW; ++ww) s += part[ww][q][0];
        out[qg] = s * (INV_4PI / (float)M_LAND);
    } else {
        float sc = 0.f, sy = 0.f;
        #pragma unroll
        for (int ww = 0; ww < NW; ++ww) {
            sc += part[ww][q][1];
            sy += part[ww][q][1 + cmp];    // Σ c*(-2 y_c)  ->  Σ c*y_c = -sy/2
        }
        const float qc = xq[3*qg + (cmp-1)];
        // grad_c = -inv4pi/M * (q_c * Σc - Σ c*y_c) = -inv4pi/M * (q_c*sc + sy/2)
        out[B + 3*qg + (cmp-1)] =
            (-INV_4PI / (float)M_LAND) * fmaf(qc, sc, 0.5f * sy);
    }
}

extern "C" void kernel_launch(void* const* d_in, const int* in_sizes, int n_in,
                              void* d_out, int out_size, void* d_ws, size_t ws_size,
                              hipStream_t stream)
{
    const float* xq = (const float*)d_in[0];   // (B,3)
    const float* xl = (const float*)d_in[1];   // (M,3)
    const float* gl = (const float*)d_in[2];   // (M,)
    float* out = (float*)d_out;                // [v_hat (B,) | gradv_hat (B,3)]

    const int B = in_sizes[0] / 3;             // 32768
    const int grid = B / QPB;                  // 256 blocks (1 per CU)

    poisson_mc_kernel<<<grid, 512, 0, stream>>>(xq, xl, gl, out, B);
}

// Round 2
// 31.242 us; speedup vs baseline: 1.0881x; 1.0881x over previous
//
#include <hip/hip_runtime.h>
#include <math.h>

// Poisson MC estimator: v_hat (B,) and gradv_hat (B,3) from pairwise
// regularized Green's function over M landmarks.
//
// R2 layout: block = 1024 threads = 16 waves (4 waves/SIMD, vs 2 in R1 —
// latency hiding was the R1 gap: only 2 waves/SIMD to cover the
// t->max->rsq->s2->s3 chain + LDS latency). Wave w owns landmark slice
// [w*128,(w+1)*128); each lane owns 2 queries (lane, lane+64).
// Landmarks staged once in LDS as TWO float4s:
//   pack  = (-2y0, -2y1, -2y2, ||y||^2 + eps^2)
//   gpack = (g*-2y0, g*-2y1, g*-2y2, g)        <- g pre-folded, saves c=g*s3
// All lanes of a wave read the same LDS address -> broadcast, no conflicts.
// Per-(wave,query) partials reduced through LDS; each output written once ->
// deterministic, no atomics, no workspace.

#define EPS2      1e-4f                    // cfg.eps^2
#define INV_4PI   0.07957747154594767f

constexpr int M_LAND = 2048;
constexpr int NW     = 16;                 // waves (slices) per block
constexpr int SLICE  = M_LAND / NW;        // 128 landmarks per wave
constexpr int QPB    = 128;                // queries per block (64 lanes x 2)

__global__ __launch_bounds__(1024, 4)
void poisson_mc_kernel(const float* __restrict__ xq,
                       const float* __restrict__ xl,
                       const float* __restrict__ gl,
                       float* __restrict__ out,
                       int B)
{
    __shared__ float4 pack[M_LAND];        // 32 KB
    __shared__ float4 gpack[M_LAND];       // 32 KB
    __shared__ float  part[NW][QPB][5];    // 40 KB: av, ac, ax, ay, az

    const int tid = threadIdx.x;

    // ---- stage landmarks (one-time, 2 per thread) ----
    for (int j = tid; j < M_LAND; j += 1024) {
        float l0 = xl[3*j + 0];
        float l1 = xl[3*j + 1];
        float l2 = xl[3*j + 2];
        float g  = gl[j];
        float n2 = l0*l0 + l1*l1 + l2*l2 + EPS2;
        pack[j]  = make_float4(-2.0f*l0, -2.0f*l1, -2.0f*l2, n2);
        gpack[j] = make_float4(-2.0f*g*l0, -2.0f*g*l1, -2.0f*g*l2, g);
    }

    const int lane  = tid & 63;
    const int w     = tid >> 6;            // wave id = landmark slice id
    const int qbase = blockIdx.x * QPB;
    const int qa    = qbase + lane;        // query A
    const int qb    = qbase + 64 + lane;   // query B

    const float a0 = xq[3*qa+0], a1 = xq[3*qa+1], a2 = xq[3*qa+2];
    const float b0 = xq[3*qb+0], b1 = xq[3*qb+1], b2 = xq[3*qb+2];
    const float qea = a0*a0 + a1*a1 + a2*a2;   // ||q||^2 (eps^2 lives in pack.w)
    const float qeb = b0*b0 + b1*b1 + b2*b2;

    __syncthreads();

    float av_a = 0.f, ac_a = 0.f, ax_a = 0.f, ay_a = 0.f, az_a = 0.f;
    float av_b = 0.f, ac_b = 0.f, ax_b = 0.f, ay_b = 0.f, az_b = 0.f;

    const int base = w * SLICE;
#pragma unroll 8
    for (int i = 0; i < SLICE; ++i) {
        const float4 p  = pack[base + i];   // broadcast ds_read_b128
        const float4 gp = gpack[base + i];  // broadcast ds_read_b128

        // query A: t = ||q||^2 - 2 q.y + ||y||^2 + eps^2   (13 VALU + rsq)
        float ta = fmaf(p.x, a0, fmaf(p.y, a1, fmaf(p.z, a2, qea))) + p.w;
        ta = fmaxf(ta, EPS2);              // == maximum(r2,0)+eps^2 exactly
        float sa  = __builtin_amdgcn_rsqf(ta);   // v_rsq_f32
        float s2a = sa * sa;
        float s3a = s2a * sa;
        av_a = fmaf(gp.w, sa,  av_a);      // Σ g·s
        ac_a = fmaf(gp.w, s3a, ac_a);      // Σ c        (c = g·s^3)
        ax_a = fmaf(s3a, gp.x, ax_a);      // Σ c·(-2y0)
        ay_a = fmaf(s3a, gp.y, ay_a);
        az_a = fmaf(s3a, gp.z, az_a);

        // query B
        float tb = fmaf(p.x, b0, fmaf(p.y, b1, fmaf(p.z, b2, qeb))) + p.w;
        tb = fmaxf(tb, EPS2);
        float sb  = __builtin_amdgcn_rsqf(tb);
        float s2b = sb * sb;
        float s3b = s2b * sb;
        av_b = fmaf(gp.w, sb,  av_b);
        ac_b = fmaf(gp.w, s3b, ac_b);
        ax_b = fmaf(s3b, gp.x, ax_b);
        ay_b = fmaf(s3b, gp.y, ay_b);
        az_b = fmaf(s3b, gp.z, az_b);
    }

    // ---- write per-(wave, query) partials ----
    part[w][lane][0] = av_a;  part[w][lane][1] = ac_a;
    part[w][lane][2] = ax_a;  part[w][lane][3] = ay_a;  part[w][lane][4] = az_a;
    part[w][lane+64][0] = av_b;  part[w][lane+64][1] = ac_b;
    part[w][lane+64][2] = ax_b;  part[w][lane+64][3] = ay_b;  part[w][lane+64][4] = az_b;

    __syncthreads();

    // ---- reduce: 512 active threads = 128 queries x 4 output components ----
    if (tid < 512) {
        const int q   = tid >> 2;              // 0..127
        const int cmp = tid & 3;               // 0: v, 1..3: grad components
        const int qg  = qbase + q;

        if (cmp == 0) {
            float s = 0.f;
            #pragma unroll
            for (int ww = 0; ww < NW; ++ww) s += part[ww][q][0];
            out[qg] = s * (INV_4PI / (float)M_LAND);
        } else {
            float sc = 0.f, sy = 0.f;
            #pragma unroll
            for (int ww = 0; ww < NW; ++ww) {
                sc += part[ww][q][1];
                sy += part[ww][q][1 + cmp];    // Σ c*(-2 y_c)
            }
            const float qc = xq[3*qg + (cmp-1)];
            // grad_c = -inv4pi/M * (q_c*Σc - Σ c*y_c) = -inv4pi/M * (q_c*Σc + sy/2)
            out[B + 3*qg + (cmp-1)] =
                (-INV_4PI / (float)M_LAND) * fmaf(qc, sc, 0.5f * sy);
        }
    }
}

extern "C" void kernel_launch(void* const* d_in, const int* in_sizes, int n_in,
                              void* d_out, int out_size, void* d_ws, size_t ws_size,
                              hipStream_t stream)
{
    const float* xq = (const float*)d_in[0];   // (B,3)
    const float* xl = (const float*)d_in[1];   // (M,3)
    const float* gl = (const float*)d_in[2];   // (M,)
    float* out = (float*)d_out;                // [v_hat (B,) | gradv_hat (B,3)]

    const int B = in_sizes[0] / 3;             // 32768
    const int grid = B / QPB;                  // 256 blocks (1 per CU)

    poisson_mc_kernel<<<grid, 1024, 0, stream>>>(xq, xl, gl, out, B);
}